// Round 6
// baseline (594.377 us; speedup 1.0000x reference)
//
#include <hip/hip_runtime.h>
#include <hip/hip_bf16.h>
#include <stdint.h>

#define NR 16384
#define DIM 512
#define BK 32
#define NT (DIM / BK)      // 16 K-tiles
#define NTILE (NR / 256)   // 64 tile rows/cols
#define TILE_US (256 * BK) // 8192 ushorts = 16 KB per matrix per buffer

typedef __bf16 bf16x8 __attribute__((ext_vector_type(8)));
typedef float f32x4 __attribute__((ext_vector_type(4)));

__device__ inline ushort f2bf(float x) {
  uint32_t u = __float_as_uint(x);
  uint32_t r = (u + 0x7FFFu + ((u >> 16) & 1u)) >> 16;
  return (ushort)r;
}

// Kernel 1: fp32 -> bf16 (RNE) for both matrices + fused diagonal dot.
__global__ __launch_bounds__(256) void convert_diag(
    const float* __restrict__ I, const float* __restrict__ T,
    const float* __restrict__ scale_p,
    ushort* __restrict__ bI, ushort* __restrict__ bT,
    float* __restrict__ diag)
{
  int wid = threadIdx.x >> 6;
  int lane = threadIdx.x & 63;
  int row = blockIdx.x * 4 + wid;
  const float4* I4 = (const float4*)(I + (size_t)row * DIM);
  const float4* T4 = (const float4*)(T + (size_t)row * DIM);
  ushort* bIr = bI + (size_t)row * DIM;
  ushort* bTr = bT + (size_t)row * DIM;
  float dot = 0.f;
#pragma unroll
  for (int h = 0; h < 2; ++h) {
    int idx = lane + h * 64;
    float4 a = I4[idx];
    float4 b = T4[idx];
    dot += a.x * b.x + a.y * b.y + a.z * b.z + a.w * b.w;
    ushort4 ha, hb;
    ha.x = f2bf(a.x); ha.y = f2bf(a.y); ha.z = f2bf(a.z); ha.w = f2bf(a.w);
    hb.x = f2bf(b.x); hb.y = f2bf(b.y); hb.z = f2bf(b.z); hb.w = f2bf(b.w);
    *(ushort4*)(bIr + (size_t)idx * 4) = ha;
    *(ushort4*)(bTr + (size_t)idx * 4) = hb;
  }
#pragma unroll
  for (int off = 32; off > 0; off >>= 1) dot += __shfl_down(dot, off);
  if (lane == 0) diag[row] = scale_p[0] * dot;
}

// Kernel 2: 256x256-tile bf16 MFMA GEMM, 8 waves (2x4), BK=32,
// triple-buffered LDS + counted vmcnt(4). NO intra-iteration scheduling
// pins: compiler software-pipelines ds_read <-> MFMA (fine-grained lgkmcnt).
// sched_barrier(0) only at K-tile boundaries (fence around s_barrier).
__global__ __launch_bounds__(512, 2) void gemm_lse(
    const ushort* __restrict__ bI, const ushort* __restrict__ bT,
    const float* __restrict__ scale_p,
    float2* __restrict__ rowPart, float2* __restrict__ colPart)
{
  __shared__ __align__(16) ushort As[3][TILE_US];
  __shared__ __align__(16) ushort Bs[3][TILE_US];

  // XCD-aware: XCD x owns an 8(bi) x 64(bj) slab; bi FAST -> ~3 MB L2 set.
  int bid = blockIdx.x;
  int x = bid & 7, s = bid >> 3;        // nwg=4096, %8==0 -> bijective
  int bi = x * 8 + (s & 7);             // 0..63
  int bj = s >> 3;                      // 0..63

  int tid = threadIdx.x;
  int w = tid >> 6, lane = tid & 63;
  int wr = w >> 2, wc = w & 3;          // 2x4 wave grid; wave tile 128x64

  const ushort* gA = bI + (size_t)bi * 256 * DIM;
  const ushort* gB = bT + (size_t)bj * 256 * DIM;

  // staging: linear LDS dest (wave-uniform base + lane*16B); SOURCE is
  // pre-swizzled so read-side XOR sees the same involution (rule #21).
  int srow = tid >> 2;
  int sslot = (tid & 3) ^ ((tid >> 3) & 3);

  auto stage = [&](ushort* dstTile, const ushort* srcMat, int kt, int h) {
    const ushort* g = srcMat + (size_t)(h * 128 + srow) * DIM + kt * BK + sslot * 8;
    ushort* d = dstTile + (h * 128 + w * 16) * BK;  // wave-uniform base
    __builtin_amdgcn_global_load_lds(
        (const __attribute__((address_space(1))) void*)g,
        (__attribute__((address_space(3))) void*)d, 16, 0, 0);
  };

  f32x4 acc[8][4];
#pragma unroll
  for (int m = 0; m < 8; ++m)
#pragma unroll
    for (int n = 0; n < 4; ++n)
      acc[m][n] = (f32x4){0.f, 0.f, 0.f, 0.f};

  // prologue: stage K-tiles 0 and 1; wait tile 0 only (4 stay in flight)
  stage(As[0], gA, 0, 0); stage(As[0], gA, 0, 1);
  stage(Bs[0], gB, 0, 0); stage(Bs[0], gB, 0, 1);
  stage(As[1], gA, 1, 0); stage(As[1], gA, 1, 1);
  stage(Bs[1], gB, 1, 0); stage(Bs[1], gB, 1, 1);
  asm volatile("s_waitcnt vmcnt(4)" ::: "memory");
  __builtin_amdgcn_sched_barrier(0);
  __builtin_amdgcn_s_barrier();
  __builtin_amdgcn_sched_barrier(0);

  int aRow0 = wr * 128 + (lane & 15);
  int bRow0 = wc * 64 + (lane & 15);
  int sLog = lane >> 4;                 // logical 16B slot within row

  auto ldFrag = [&](const ushort* tile, int row) -> bf16x8 {
    int off = row * (BK * 2) + ((sLog ^ ((row >> 1) & 3)) << 4);
    return *(const bf16x8*)((const char*)tile + off);
  };

  int buf = 0, nb = 2;
  for (int t = 0; t < NT; ++t) {
    const ushort* At = As[buf];
    const ushort* Bt = Bs[buf];
    ushort* An = As[nb];
    ushort* Bn = Bs[nb];
    bool pf = (t + 2 < NT);

    // issue next-next tile staging early (HBM latency hides under compute)
    if (pf) {
      stage(An, gA, t + 2, 0); stage(An, gA, t + 2, 1);
      stage(Bn, gB, t + 2, 0); stage(Bn, gB, t + 2, 1);
    }

    // fragment loads + MFMAs, UNPINNED: compiler interleaves with
    // fine-grained lgkmcnt so LDS pipe overlaps matrix pipe.
    bf16x8 aF[4], bF[4], aG[4];
#pragma unroll
    for (int m = 0; m < 4; ++m) aF[m] = ldFrag(At, aRow0 + m * 16);
#pragma unroll
    for (int n = 0; n < 4; ++n) bF[n] = ldFrag(Bt, bRow0 + n * 16);
#pragma unroll
    for (int m = 0; m < 4; ++m) aG[m] = ldFrag(At, aRow0 + 64 + m * 16);

#pragma unroll
    for (int m = 0; m < 4; ++m)
#pragma unroll
      for (int n = 0; n < 4; ++n)
        acc[m][n] = __builtin_amdgcn_mfma_f32_16x16x32_bf16(aF[m], bF[n], acc[m][n], 0, 0, 0);
#pragma unroll
    for (int m = 0; m < 4; ++m)
#pragma unroll
      for (int n = 0; n < 4; ++n)
        acc[m + 4][n] = __builtin_amdgcn_mfma_f32_16x16x32_bf16(aG[m], bF[n], acc[m + 4][n], 0, 0, 0);

    // ---- K-tile boundary: counted wait (t+1 landed; t+2 in flight) ----
    __builtin_amdgcn_sched_barrier(0);
    if (pf) asm volatile("s_waitcnt vmcnt(4)" ::: "memory");
    else    asm volatile("s_waitcnt vmcnt(0)" ::: "memory");
    __builtin_amdgcn_sched_barrier(0);
    __builtin_amdgcn_s_barrier();
    __builtin_amdgcn_sched_barrier(0);   // no ds_read hoists above barrier

    buf = (buf == 2) ? 0 : buf + 1;
    nb  = (nb == 2) ? 0 : nb + 1;
  }

  // ---- epilogue: scale + per-tile row/col (max, sumexp) partials ----
  float sc = scale_p[0];
#pragma unroll
  for (int m = 0; m < 8; ++m)
#pragma unroll
    for (int n = 0; n < 4; ++n)
      acc[m][n] *= sc;

  float2* redRow = (float2*)&As[0][0];  // [256][4]
  float2* redCol = (float2*)&Bs[0][0];  // [256][2]

  // C/D layout: col = lane&15, row = (lane>>4)*4 + reg.
#pragma unroll
  for (int m = 0; m < 8; ++m) {
#pragma unroll
    for (int j = 0; j < 4; ++j) {
      float rm = fmaxf(fmaxf(acc[m][0][j], acc[m][1][j]),
                       fmaxf(acc[m][2][j], acc[m][3][j]));
#pragma unroll
      for (int msk = 1; msk <= 8; msk <<= 1) rm = fmaxf(rm, __shfl_xor(rm, msk));
      float rs = 0.f;
#pragma unroll
      for (int n = 0; n < 4; ++n) rs += __expf(acc[m][n][j] - rm);
#pragma unroll
      for (int msk = 1; msk <= 8; msk <<= 1) rs += __shfl_xor(rs, msk);
      if ((lane & 15) == 0) {
        int r = wr * 128 + m * 16 + (lane >> 4) * 4 + j;
        redRow[r * 4 + wc] = make_float2(rm, rs);
      }
    }
  }
#pragma unroll
  for (int n = 0; n < 4; ++n) {
    float cm = -1e30f;
#pragma unroll
    for (int m = 0; m < 8; ++m)
#pragma unroll
      for (int j = 0; j < 4; ++j) cm = fmaxf(cm, acc[m][n][j]);
    cm = fmaxf(cm, __shfl_xor(cm, 16));
    cm = fmaxf(cm, __shfl_xor(cm, 32));
    float cs = 0.f;
#pragma unroll
    for (int m = 0; m < 8; ++m)
#pragma unroll
      for (int j = 0; j < 4; ++j) cs += __expf(acc[m][n][j] - cm);
    cs += __shfl_xor(cs, 16);
    cs += __shfl_xor(cs, 32);
    if (lane < 16) {
      int c = wc * 64 + n * 16 + lane;
      redCol[c * 2 + wr] = make_float2(cm, cs);
    }
  }
  __syncthreads();

  if (tid < 256) {
    float2 p = redRow[tid * 4];
    float m_ = p.x, s_ = p.y;
#pragma unroll
    for (int q = 1; q < 4; ++q) {
      float2 r = redRow[tid * 4 + q];
      float mn = fmaxf(m_, r.x);
      s_ = s_ * __expf(m_ - mn) + r.y * __expf(r.x - mn);
      m_ = mn;
    }
    rowPart[(size_t)bj * NR + bi * 256 + tid] = make_float2(m_, s_);
  } else {
    int c = tid - 256;
    float2 p0 = redCol[c * 2], p1 = redCol[c * 2 + 1];
    float mn = fmaxf(p0.x, p1.x);
    float s_ = p0.y * __expf(p0.x - mn) + p1.y * __expf(p1.x - mn);
    colPart[(size_t)bi * NR + bj * 256 + c] = make_float2(mn, s_);
  }
}

// Kernel 3: merge 64 partials per row/col, subtract diag, accumulate mean.
__global__ __launch_bounds__(256) void reduce_final(
    const float2* __restrict__ rowPart, const float2* __restrict__ colPart,
    const float* __restrict__ diag, float* __restrict__ out)
{
  int bid = blockIdx.x;            // 0..127; first 64 rows, last 64 cols
  bool isCol = bid >= 64;
  int i = (bid & 63) * 256 + threadIdx.x;
  const float2* part = isCol ? colPart : rowPart;
  float m = -1e30f, s = 0.f;
  for (int b = 0; b < NTILE; ++b) {
    float2 p = part[(size_t)b * NR + i];
    float mn = fmaxf(m, p.x);
    s = s * __expf(m - mn) + p.y * __expf(p.x - mn);
    m = mn;
  }
  float contrib = (m + __logf(s)) - diag[i];
#pragma unroll
  for (int off = 32; off > 0; off >>= 1) contrib += __shfl_down(contrib, off);
  __shared__ float wsum[4];
  int wid = threadIdx.x >> 6, lane = threadIdx.x & 63;
  if (lane == 0) wsum[wid] = contrib;
  __syncthreads();
  if (threadIdx.x == 0) {
    float tot = wsum[0] + wsum[1] + wsum[2] + wsum[3];
    atomicAdd(out, tot * (1.0f / (2.0f * NR)));
  }
}

extern "C" void kernel_launch(void* const* d_in, const int* in_sizes, int n_in,
                              void* d_out, int out_size, void* d_ws, size_t ws_size,
                              hipStream_t stream) {
  const float* I = (const float*)d_in[0];
  const float* T = (const float*)d_in[1];
  const float* scale = (const float*)d_in[2];
  float* out = (float*)d_out;

  char* ws = (char*)d_ws;
  ushort* bI      = (ushort*)(ws);                          // 16 MB
  ushort* bT      = (ushort*)(ws + ((size_t)16 << 20));     // 16 MB
  float2* rowPart = (float2*)(ws + ((size_t)32 << 20));     // 8 MB used
  float2* colPart = (float2*)(ws + ((size_t)48 << 20));     // 8 MB used
  float*  diag    = (float*) (ws + ((size_t)64 << 20));     // 64 KB

  hipMemsetAsync(d_out, 0, sizeof(float), stream);
  convert_diag<<<NR / 4, 256, 0, stream>>>(I, T, scale, bI, bT, diag);
  gemm_lse<<<NTILE * NTILE, 512, 0, stream>>>(bI, bT, scale, rowPart, colPart);
  reduce_final<<<128, 256, 0, stream>>>(rowPart, colPart, diag, out);
}

// Round 10
// 540.288 us; speedup vs baseline: 1.1001x; 1.1001x over previous
//
#include <hip/hip_runtime.h>
#include <hip/hip_bf16.h>
#include <stdint.h>

#define NR 16384
#define DIM 512
#define BK 64
#define NT8 (DIM / BK)     // 8 K-tiles of 64
#define NTILE (NR / 256)   // 64 tile rows/cols

typedef __bf16 bf16x8 __attribute__((ext_vector_type(8)));
typedef float f32x4 __attribute__((ext_vector_type(4)));

__device__ inline ushort f2bf(float x) {
  uint32_t u = __float_as_uint(x);
  uint32_t r = (u + 0x7FFFu + ((u >> 16) & 1u)) >> 16;
  return (ushort)r;
}

#define MFMA __builtin_amdgcn_mfma_f32_16x16x32_bf16
#define SB() __builtin_amdgcn_sched_barrier(0)
#define BAR() __builtin_amdgcn_s_barrier()

// Kernel 1: fp32 -> bf16 (RNE) for both matrices + fused diagonal dot.
__global__ __launch_bounds__(256) void convert_diag(
    const float* __restrict__ I, const float* __restrict__ T,
    const float* __restrict__ scale_p,
    ushort* __restrict__ bI, ushort* __restrict__ bT,
    float* __restrict__ diag)
{
  int wid = threadIdx.x >> 6;
  int lane = threadIdx.x & 63;
  int row = blockIdx.x * 4 + wid;
  const float4* I4 = (const float4*)(I + (size_t)row * DIM);
  const float4* T4 = (const float4*)(T + (size_t)row * DIM);
  ushort* bIr = bI + (size_t)row * DIM;
  ushort* bTr = bT + (size_t)row * DIM;
  float dot = 0.f;
#pragma unroll
  for (int h = 0; h < 2; ++h) {
    int idx = lane + h * 64;
    float4 a = I4[idx];
    float4 b = T4[idx];
    dot += a.x * b.x + a.y * b.y + a.z * b.z + a.w * b.w;
    ushort4 ha, hb;
    ha.x = f2bf(a.x); ha.y = f2bf(a.y); ha.z = f2bf(a.z); ha.w = f2bf(a.w);
    hb.x = f2bf(b.x); hb.y = f2bf(b.y); hb.z = f2bf(b.z); hb.w = f2bf(b.w);
    *(ushort4*)(bIr + (size_t)idx * 4) = ha;
    *(ushort4*)(bTr + (size_t)idx * 4) = hb;
  }
#pragma unroll
  for (int off = 32; off > 0; off >>= 1) dot += __shfl_down(dot, off);
  if (lane == 0) diag[row] = scale_p[0] * dot;
}

// Kernel 2: 256x256 tile, BK=64, 8 waves (2x4). m201-style 4-phase/K-tile
// schedule: per phase {ds_read quadrant || stage half-tile} -> barrier ->
// lgkmcnt(0) -> setprio(1) 16 MFMA setprio(0) -> barrier. Counted vmcnt(8)
// at tile boundary only (never drains in main loop). Double-buffered
// half-tile LDS; tile t+2 staged into slots freed by tile t's reads
// (B-halves dead after P1 -> staged P2; A-halves dead after P2 -> staged P3).
__global__ __launch_bounds__(512, 2) void gemm_lse(
    const ushort* __restrict__ bI, const ushort* __restrict__ bT,
    const float* __restrict__ scale_p,
    float2* __restrict__ rowPart, float2* __restrict__ colPart)
{
  __shared__ __align__(16) ushort As[2][2][128][64];  // [buf][half][row][col]
  __shared__ __align__(16) ushort Bs[2][2][128][64];

  // XCD-aware: XCD x owns an 8(bi) x 64(bj) slab; bi FAST -> ~3 MB L2 set.
  int bid = blockIdx.x;
  int x = bid & 7, s = bid >> 3;        // nwg=4096, %8==0 -> bijective
  int bi = x * 8 + (s & 7);
  int bj = s >> 3;

  int tid = threadIdx.x;
  int w = tid >> 6, lane = tid & 63;
  int wr = w >> 2, wc = w & 3;          // 2x4 wave grid; wave tile 128x64

  const ushort* gA = bI + (size_t)bi * 256 * DIM;
  const ushort* gB = bT + (size_t)bj * 256 * DIM;

  // Staging: linear LDS dest (wave-uniform base + lane*16B). Source col-slot
  // pre-swizzled with the involution slot^=(row&7) so swizzled reads see
  // logical data (rule #21). row&7 == (tid>>3)&7 on the write side.
  int sslot3 = (tid & 7) ^ ((tid >> 3) & 7);
  int srow = tid >> 3;                  // 0..63 within a 64-row chunk

  auto stageHalf = [&](ushort* dstHalf, const ushort* srcMat, int kt, int half) {
#pragma unroll
    for (int L = 0; L < 2; ++L) {
      int row = L * 64 + srow;
      const ushort* g = srcMat + (size_t)(half * 128 + row) * DIM + kt * BK + sslot3 * 8;
      ushort* d = dstHalf + L * 4096 + w * 512;   // ushorts
      __builtin_amdgcn_global_load_lds(
          (const __attribute__((address_space(1))) void*)g,
          (__attribute__((address_space(3))) void*)d, 16, 0, 0);
    }
  };

  f32x4 acc[8][4];
#pragma unroll
  for (int m = 0; m < 8; ++m)
#pragma unroll
    for (int n = 0; n < 4; ++n)
      acc[m][n] = (f32x4){0.f, 0.f, 0.f, 0.f};

  // prologue: stage tiles 0 and 1 fully; wait tile 0 only (8 stay in flight)
  stageHalf(&As[0][0][0][0], gA, 0, 0); stageHalf(&As[0][1][0][0], gA, 0, 1);
  stageHalf(&Bs[0][0][0][0], gB, 0, 0); stageHalf(&Bs[0][1][0][0], gB, 0, 1);
  stageHalf(&Bs[1][0][0][0], gB, 1, 0); stageHalf(&Bs[1][1][0][0], gB, 1, 1);
  stageHalf(&As[1][0][0][0], gA, 1, 0); stageHalf(&As[1][1][0][0], gA, 1, 1);
  asm volatile("s_waitcnt vmcnt(8)" ::: "memory");
  SB(); BAR(); SB();

  // Fragment read: byte offset within a half for 16-row block b, k-step k.
  int l15 = lane & 15, l7 = lane & 7, lq = lane >> 4;
  auto fragOff = [&](int b16, int k) -> int {
    int ks = k * 4 + lq;                 // logical 16B slot (0..7)
    return b16 * 2048 + l15 * 128 + ((ks ^ l7) << 4);
  };

  for (int t = 0; t < NT8; ++t) {
    int buf = t & 1;
    const char* At = (const char*)&As[buf][wr][0][0];
    const char* Bt = (const char*)&Bs[buf][wc >> 1][0][0] + (wc & 1) * 8192;
    bool pf = (t + 2 < NT8);             // tile t+2 buf == buf (reuse freed slots)

    bf16x8 aLo[8], aHi[8], bLo[4], bHi[4];

    // ================= P0: Q0 = m0-3 x n0-1 =================
#pragma unroll
    for (int m = 0; m < 4; ++m)
#pragma unroll
      for (int k = 0; k < 2; ++k)
        aLo[m * 2 + k] = *(const bf16x8*)(At + fragOff(m, k));
#pragma unroll
    for (int n = 0; n < 2; ++n)
#pragma unroll
      for (int k = 0; k < 2; ++k)
        bLo[n * 2 + k] = *(const bf16x8*)(Bt + fragOff(n, k));
    SB(); BAR();
    asm volatile("s_waitcnt lgkmcnt(0)" ::: "memory");
    SB();
    __builtin_amdgcn_s_setprio(1);
#pragma unroll
    for (int m = 0; m < 4; ++m)
#pragma unroll
      for (int n = 0; n < 2; ++n)
#pragma unroll
        for (int k = 0; k < 2; ++k)
          acc[m][n] = MFMA(aLo[m * 2 + k], bLo[n * 2 + k], acc[m][n], 0, 0, 0);
    __builtin_amdgcn_s_setprio(0);
    SB(); BAR(); SB();

    // ================= P1: Q1 = m0-3 x n2-3 =================
#pragma unroll
    for (int n = 2; n < 4; ++n)
#pragma unroll
      for (int k = 0; k < 2; ++k)
        bHi[(n - 2) * 2 + k] = *(const bf16x8*)(Bt + fragOff(n, k));
    SB(); BAR();
    asm volatile("s_waitcnt lgkmcnt(0)" ::: "memory");
    SB();
    __builtin_amdgcn_s_setprio(1);
#pragma unroll
    for (int m = 0; m < 4; ++m)
#pragma unroll
      for (int n = 2; n < 4; ++n)
#pragma unroll
        for (int k = 0; k < 2; ++k)
          acc[m][n] = MFMA(aLo[m * 2 + k], bHi[(n - 2) * 2 + k], acc[m][n], 0, 0, 0);
    __builtin_amdgcn_s_setprio(0);
    SB(); BAR(); SB();

    // ================= P2: Q2 = m4-7 x n0-1; stage B(t+2) =================
#pragma unroll
    for (int m = 4; m < 8; ++m)
#pragma unroll
      for (int k = 0; k < 2; ++k)
        aHi[(m - 4) * 2 + k] = *(const bf16x8*)(At + fragOff(m, k));
    if (pf) {                            // B-halves of buf free after P1
      stageHalf(&Bs[buf][0][0][0], gB, t + 2, 0);
      stageHalf(&Bs[buf][1][0][0], gB, t + 2, 1);
    }
    SB(); BAR();
    asm volatile("s_waitcnt lgkmcnt(0)" ::: "memory");
    SB();
    __builtin_amdgcn_s_setprio(1);
#pragma unroll
    for (int m = 4; m < 8; ++m)
#pragma unroll
      for (int n = 0; n < 2; ++n)
#pragma unroll
        for (int k = 0; k < 2; ++k)
          acc[m][n] = MFMA(aHi[(m - 4) * 2 + k], bLo[n * 2 + k], acc[m][n], 0, 0, 0);
    __builtin_amdgcn_s_setprio(0);
    SB(); BAR(); SB();

    // ================= P3: Q3 = m4-7 x n2-3; stage A(t+2); counted vmcnt ====
    if (pf) {                            // A-halves of buf free after P2
      stageHalf(&As[buf][0][0][0], gA, t + 2, 0);
      stageHalf(&As[buf][1][0][0], gA, t + 2, 1);
    }
    SB();
    if (pf) asm volatile("s_waitcnt vmcnt(8)" ::: "memory");  // tile t+1 landed
    else    asm volatile("s_waitcnt vmcnt(0)" ::: "memory");  // tail drain
    SB(); BAR(); SB();
    __builtin_amdgcn_s_setprio(1);
#pragma unroll
    for (int m = 4; m < 8; ++m)
#pragma unroll
      for (int n = 2; n < 4; ++n)
#pragma unroll
        for (int k = 0; k < 2; ++k)
          acc[m][n] = MFMA(aHi[(m - 4) * 2 + k], bHi[(n - 2) * 2 + k], acc[m][n], 0, 0, 0);
    __builtin_amdgcn_s_setprio(0);
    SB(); BAR(); SB();
  }

  // ---- epilogue: scale + per-tile row/col (max, sumexp) partials ----
  float sc = scale_p[0];
#pragma unroll
  for (int m = 0; m < 8; ++m)
#pragma unroll
    for (int n = 0; n < 4; ++n)
      acc[m][n] *= sc;

  float2* redRow = (float2*)&As[0][0][0][0];  // [256][4]
  float2* redCol = (float2*)&Bs[0][0][0][0];  // [256][2]

  // C/D layout: col = lane&15, row = (lane>>4)*4 + reg.
#pragma unroll
  for (int m = 0; m < 8; ++m) {
#pragma unroll
    for (int j = 0; j < 4; ++j) {
      float rm = fmaxf(fmaxf(acc[m][0][j], acc[m][1][j]),
                       fmaxf(acc[m][2][j], acc[m][3][j]));
#pragma unroll
      for (int msk = 1; msk <= 8; msk <<= 1) rm = fmaxf(rm, __shfl_xor(rm, msk));
      float rs = 0.f;
#pragma unroll
      for (int n = 0; n < 4; ++n) rs += __expf(acc[m][n][j] - rm);
#pragma unroll
      for (int msk = 1; msk <= 8; msk <<= 1) rs += __shfl_xor(rs, msk);
      if ((lane & 15) == 0) {
        int r = wr * 128 + m * 16 + (lane >> 4) * 4 + j;
        redRow[r * 4 + wc] = make_float2(rm, rs);
      }
    }
  }
#pragma unroll
  for (int n = 0; n < 4; ++n) {
    float cm = -1e30f;
#pragma unroll
    for (int m = 0; m < 8; ++m)
#pragma unroll
      for (int j = 0; j < 4; ++j) cm = fmaxf(cm, acc[m][n][j]);
    cm = fmaxf(cm, __shfl_xor(cm, 16));
    cm = fmaxf(cm, __shfl_xor(cm, 32));
    float cs = 0.f;
#pragma unroll
    for (int m = 0; m < 8; ++m)
#pragma unroll
      for (int j = 0; j < 4; ++j) cs += __expf(acc[m][n][j] - cm);
    cs += __shfl_xor(cs, 16);
    cs += __shfl_xor(cs, 32);
    if (lane < 16) {
      int c = wc * 64 + n * 16 + lane;
      redCol[c * 2 + wr] = make_float2(cm, cs);
    }
  }
  __syncthreads();

  if (tid < 256) {
    float2 p = redRow[tid * 4];
    float m_ = p.x, s_ = p.y;
#pragma unroll
    for (int q = 1; q < 4; ++q) {
      float2 r = redRow[tid * 4 + q];
      float mn = fmaxf(m_, r.x);
      s_ = s_ * __expf(m_ - mn) + r.y * __expf(r.x - mn);
      m_ = mn;
    }
    rowPart[(size_t)bj * NR + bi * 256 + tid] = make_float2(m_, s_);
  } else {
    int c = tid - 256;
    float2 p0 = redCol[c * 2], p1 = redCol[c * 2 + 1];
    float mn = fmaxf(p0.x, p1.x);
    float s_ = p0.y * __expf(p0.x - mn) + p1.y * __expf(p1.x - mn);
    colPart[(size_t)bi * NR + bj * 256 + c] = make_float2(mn, s_);
  }
}

// Kernel 3: merge 64 partials per row/col, subtract diag, accumulate mean.
__global__ __launch_bounds__(256) void reduce_final(
    const float2* __restrict__ rowPart, const float2* __restrict__ colPart,
    const float* __restrict__ diag, float* __restrict__ out)
{
  int bid = blockIdx.x;            // 0..127; first 64 rows, last 64 cols
  bool isCol = bid >= 64;
  int i = (bid & 63) * 256 + threadIdx.x;
  const float2* part = isCol ? colPart : rowPart;
  float m = -1e30f, s = 0.f;
  for (int b = 0; b < NTILE; ++b) {
    float2 p = part[(size_t)b * NR + i];
    float mn = fmaxf(m, p.x);
    s = s * __expf(m - mn) + p.y * __expf(p.x - mn);
    m = mn;
  }
  float contrib = (m + __logf(s)) - diag[i];
#pragma unroll
  for (int off = 32; off > 0; off >>= 1) contrib += __shfl_down(contrib, off);
  __shared__ float wsum[4];
  int wid = threadIdx.x >> 6, lane = threadIdx.x & 63;
  if (lane == 0) wsum[wid] = contrib;
  __syncthreads();
  if (threadIdx.x == 0) {
    float tot = wsum[0] + wsum[1] + wsum[2] + wsum[3];
    atomicAdd(out, tot * (1.0f / (2.0f * NR)));
  }
}

extern "C" void kernel_launch(void* const* d_in, const int* in_sizes, int n_in,
                              void* d_out, int out_size, void* d_ws, size_t ws_size,
                              hipStream_t stream) {
  const float* I = (const float*)d_in[0];
  const float* T = (const float*)d_in[1];
  const float* scale = (const float*)d_in[2];
  float* out = (float*)d_out;

  char* ws = (char*)d_ws;
  ushort* bI      = (ushort*)(ws);                          // 16 MB
  ushort* bT      = (ushort*)(ws + ((size_t)16 << 20));     // 16 MB
  float2* rowPart = (float2*)(ws + ((size_t)32 << 20));     // 8 MB used
  float2* colPart = (float2*)(ws + ((size_t)48 << 20));     // 8 MB used
  float*  diag    = (float*) (ws + ((size_t)64 << 20));     // 64 KB

  hipMemsetAsync(d_out, 0, sizeof(float), stream);
  convert_diag<<<NR / 4, 256, 0, stream>>>(I, T, scale, bI, bT, diag);
  gemm_lse<<<NTILE * NTILE, 512, 0, stream>>>(bI, bT, scale, rowPart, colPart);
  reduce_final<<<128, 256, 0, stream>>>(rowPart, colPart, diag, out);
}